// Round 7
// baseline (11355.591 us; speedup 1.0000x reference)
//
#include <hip/hip_runtime.h>

#define HSTEPS 8640
#define HID 128
#define BATCH 16
#define NTHR 512
#define YRING 192

typedef _Float16 h16;
typedef __attribute__((ext_vector_type(8))) _Float16 h16x8;
typedef __attribute__((ext_vector_type(4))) float f32x4;

static __device__ __forceinline__ float sigm(float x) {
    return __builtin_amdgcn_rcpf(1.0f + __expf(-x));
}
static __device__ __forceinline__ float tanh_f(float x) {
    float ax = __builtin_fabsf(x);
    float ee = __expf(2.0f * ax);
    float r = 1.0f - 2.0f * __builtin_amdgcn_rcpf(ee + 1.0f);
    return __builtin_copysignf(r, x);
}
template <int CTRL>
static __device__ __forceinline__ float dppmov(float x) {
    return __int_as_float(
        __builtin_amdgcn_mov_dpp(__float_as_int(x), CTRL, 0xF, 0xF, false));
}
static __device__ __forceinline__ float sum8(float x) {
    x += dppmov<0x121>(x);
    x += dppmov<0x122>(x);
    x += dppmov<0x124>(x);
    return x;
}
static __device__ __forceinline__ float sum16(float x) {
    x += dppmov<0x121>(x);
    x += dppmov<0x122>(x);
    x += dppmov<0x124>(x);
    x += dppmov<0x128>(x);
    return x;
}

// ---- weight fragments: 48 named h16x8 (MFMA-B only -> AGPR-eligible) ----
#define FRAG_GC(F, m, g) F(m, g, 0) F(m, g, 1) F(m, g, 2) F(m, g, 3)
#define FRAG_M(F, m) FRAG_GC(F, m, 0) FRAG_GC(F, m, 1) FRAG_GC(F, m, 2) FRAG_GC(F, m, 3)
#define FRAG_ALL(F) FRAG_M(F, 0) FRAG_M(F, 1) FRAG_M(F, 2)

#define DECLF(m, g, c) h16x8 wf##m##_##g##_##c;

#define WPTR0 Whh0
#define WPTR1 Wih1
#define WPTR2 Whh1
// B[k][n]: lane l holds W[16*(wv+8g) + (l&15)][32c + 8*(l>>4) + j], j=0..7
#define LOADF(m, g, c)                                                         \
    {                                                                          \
        const float* p_ = WPTR##m +                                            \
            (size_t)((16 * (wv + 8 * g) + ln15) * HID + 32 * c + 8 * grp);     \
        float4 u_ = *(const float4*)p_;                                        \
        float4 v_ = *(const float4*)(p_ + 4);                                  \
        wf##m##_##g##_##c = h16x8{(h16)u_.x, (h16)u_.y, (h16)u_.z, (h16)u_.w,  \
                                  (h16)v_.x, (h16)v_.y, (h16)v_.z, (h16)v_.w}; \
    }

// one h-chunk feeds all 4 gate chains (4 independent MFMAs per chunk)
#define MFMA4(QA, QB, QC, QD, av, m, c)                                        \
    QA = __builtin_amdgcn_mfma_f32_16x16x32_f16((av), wf##m##_0_##c, QA, 0, 0, 0); \
    QB = __builtin_amdgcn_mfma_f32_16x16x32_f16((av), wf##m##_1_##c, QB, 0, 0, 0); \
    QC = __builtin_amdgcn_mfma_f32_16x16x32_f16((av), wf##m##_2_##c, QC, 0, 0, 0); \
    QD = __builtin_amdgcn_mfma_f32_16x16x32_f16((av), wf##m##_3_##c, QD, 0, 0, 0);

// One block per batch; 512 threads = 8 waves, 2/SIMD (256 unified regs cap).
// Peak demand by construction: 192 fragments + 16 acc + ~8 operands + ~25
// working < 256 -> no spill. Biases/Wih0 live in LDS, re-read each step.
__global__ __launch_bounds__(NTHR, 2) void lstm2_kernel(
    const float* __restrict__ y0, const float* __restrict__ h0in,
    const float* __restrict__ c0in, const float* __restrict__ Wih0,
    const float* __restrict__ Whh0, const float* __restrict__ bih0,
    const float* __restrict__ bhh0, const float* __restrict__ Wih1,
    const float* __restrict__ Whh1, const float* __restrict__ bih1,
    const float* __restrict__ bhh1, const float* __restrict__ fcw,
    const float* __restrict__ fcb, float* __restrict__ out) {
    const int b = blockIdx.x;
    const int t = threadIdx.x;
    const int wv = t >> 6;
    const int ln = t & 63;
    const int grp = ln >> 4;
    const int ln15 = ln & 15;
    const int ev = 16 * wv + ln15;  // this lane's element 0..127

    // hsm: [0..127]=h0 buf0, [128..255]=h0 buf1, [256..383]=h1 buf0, [384..511]=h1 buf1
    __shared__ __align__(16) h16 hsm[512];
    __shared__ float ypartbuf[8];
    __shared__ float ybuf[YRING];
    __shared__ __align__(16) float bias0v[HID][4];  // [e][g]
    __shared__ __align__(16) float bias1v[HID][4];
    __shared__ __align__(16) float wih0v[HID][4];

    FRAG_ALL(DECLF)
    FRAG_ALL(LOADF)

    const float fcb_ = fcb[0];
    const float fcw_e = fcw[ev];

    float c0v = c0in[b * HID + ev];            // replicated across k-groups
    float c1v = c0in[(BATCH + b) * HID + ev];  // replicated across k-groups

    if (t < HID) {
#pragma unroll
        for (int g = 0; g < 4; ++g) {
            bias0v[t][g] = bih0[g * 128 + t] + bhh0[g * 128 + t];
            bias1v[t][g] = bih1[g * 128 + t] + bhh1[g * 128 + t];
            wih0v[t][g] = Wih0[g * 128 + t];
        }
    }
    if (ln < 16) {
        hsm[ev] = (h16)h0in[b * HID + ev];
        hsm[256 + ev] = (h16)h0in[(BATCH + b) * HID + ev];
    }
    if (t < 8) ypartbuf[t] = (t == 0) ? (y0[b] - fcb_) : 0.0f;
    __syncthreads();

    float* outb = out + (size_t)b * HSTEPS;
    int p = 0;
    int ys = 0;
    int flush_at = YRING;

#pragma unroll 1
    for (int s = 0; s < HSTEPS; ++s) {
        // ---- y = fc output of previous step ----
        float yv = sum8(ypartbuf[ln & 7]) + fcb_;
        if (s > 0) {
            if (t == 0) ybuf[ys] = yv;
            ys = (ys == YRING - 1) ? 0 : ys + 1;
        }

        const int hp0 = 8 * grp + 128 * p;  // h0 buf p, this lane's k-slice

        // ---- phase A: gates0 = Whh0 @ h0_prev (+ Wih0*y + bias0) ----
        f32x4 q0 = {0.f, 0.f, 0.f, 0.f}, q1 = {0.f, 0.f, 0.f, 0.f};
        f32x4 q2 = {0.f, 0.f, 0.f, 0.f}, q3 = {0.f, 0.f, 0.f, 0.f};
        {
            h16x8 av;
            av = *(const h16x8*)&hsm[hp0 + 0];
            MFMA4(q0, q1, q2, q3, av, 0, 0)
            av = *(const h16x8*)&hsm[hp0 + 32];
            MFMA4(q0, q1, q2, q3, av, 0, 1)
            av = *(const h16x8*)&hsm[hp0 + 64];
            MFMA4(q0, q1, q2, q3, av, 0, 2)
            av = *(const h16x8*)&hsm[hp0 + 96];
            MFMA4(q0, q1, q2, q3, av, 0, 3)
        }
        // bias reads issued after MFMA issue -> latency overlaps chain drain
        float4 wv4 = *(const float4*)&wih0v[ev][0];
        float4 bb0 = *(const float4*)&bias0v[ev][0];
        float G0 = q0[0] + __builtin_fmaf(wv4.x, yv, bb0.x);
        float G1 = q1[0] + __builtin_fmaf(wv4.y, yv, bb0.y);
        float G2 = q2[0] + __builtin_fmaf(wv4.z, yv, bb0.z);
        float G3 = q3[0] + __builtin_fmaf(wv4.w, yv, bb0.w);
        float si = sigm(G0), sf = sigm(G1), so = sigm(G3);
        float tg = tanh_f(G2);
        c0v = __builtin_fmaf(sf, c0v, si * tg);
        float h0nv = so * tanh_f(c0v);
        if (ln < 16) hsm[(p ^ 1) * 128 + ev] = (h16)h0nv;
        __syncthreads();  // B1: h0 new ready

        // ---- periodic output flush (uniform, 1/192 steps) ----
        if (s == flush_at) {
            if (t < YRING) outb[flush_at - YRING + t] = ybuf[t];
            flush_at += YRING;
        }

        // ---- phase B: gates1 = Whh1 @ h1_prev + Wih1 @ h0n + bias1 ----
        q0 = (f32x4){0.f, 0.f, 0.f, 0.f};
        q1 = (f32x4){0.f, 0.f, 0.f, 0.f};
        q2 = (f32x4){0.f, 0.f, 0.f, 0.f};
        q3 = (f32x4){0.f, 0.f, 0.f, 0.f};
        {
            h16x8 av;
            av = *(const h16x8*)&hsm[hp0 + 256];  // h1 buf p
            MFMA4(q0, q1, q2, q3, av, 2, 0)
            av = *(const h16x8*)&hsm[hp0 + 288];
            MFMA4(q0, q1, q2, q3, av, 2, 1)
            av = *(const h16x8*)&hsm[hp0 + 320];
            MFMA4(q0, q1, q2, q3, av, 2, 2)
            av = *(const h16x8*)&hsm[hp0 + 352];
            MFMA4(q0, q1, q2, q3, av, 2, 3)
            const int hb = hp0 ^ 128;  // h0 buf p^1
            av = *(const h16x8*)&hsm[hb + 0];
            MFMA4(q0, q1, q2, q3, av, 1, 0)
            av = *(const h16x8*)&hsm[hb + 32];
            MFMA4(q0, q1, q2, q3, av, 1, 1)
            av = *(const h16x8*)&hsm[hb + 64];
            MFMA4(q0, q1, q2, q3, av, 1, 2)
            av = *(const h16x8*)&hsm[hb + 96];
            MFMA4(q0, q1, q2, q3, av, 1, 3)
        }
        float4 bb1 = *(const float4*)&bias1v[ev][0];
        float H0 = q0[0] + bb1.x;
        float H1 = q1[0] + bb1.y;
        float H2 = q2[0] + bb1.z;
        float H3 = q3[0] + bb1.w;
        float ti = sigm(H0), tf = sigm(H1), to = sigm(H3);
        float tgg = tanh_f(H2);
        c1v = __builtin_fmaf(tf, c1v, ti * tgg);
        float h1nv = to * tanh_f(c1v);
        if (ln < 16) hsm[256 + (p ^ 1) * 128 + ev] = (h16)h1nv;

        float part = sum16(fcw_e * h1nv);
        if (ln == 0) ypartbuf[wv] = part;

        p ^= 1;
        __syncthreads();  // B2: h1/ypart ready
    }

    // ---- tail: y(8639) + final flush ----
    float yv = sum8(ypartbuf[ln & 7]) + fcb_;
    if (t == 0) ybuf[YRING - 1] = yv;
    __syncthreads();
    if (t < YRING) outb[HSTEPS - YRING + t] = ybuf[t];
}

extern "C" void kernel_launch(void* const* d_in, const int* in_sizes, int n_in,
                              void* d_out, int out_size, void* d_ws,
                              size_t ws_size, hipStream_t stream) {
    const float* y0 = (const float*)d_in[0];
    const float* h0 = (const float*)d_in[1];
    const float* c0 = (const float*)d_in[2];
    const float* Wih0 = (const float*)d_in[3];
    const float* Whh0 = (const float*)d_in[4];
    const float* bih0 = (const float*)d_in[5];
    const float* bhh0 = (const float*)d_in[6];
    const float* Wih1 = (const float*)d_in[7];
    const float* Whh1 = (const float*)d_in[8];
    const float* bih1 = (const float*)d_in[9];
    const float* bhh1 = (const float*)d_in[10];
    const float* fcw = (const float*)d_in[11];
    const float* fcb = (const float*)d_in[12];
    float* out = (float*)d_out;

    lstm2_kernel<<<dim3(BATCH), dim3(NTHR), 0, stream>>>(
        y0, h0, c0, Wih0, Whh0, bih0, bhh0, Wih1, Whh1, bih1, bhh1, fcw, fcb,
        out);
}